// Round 10
// baseline (392.627 us; speedup 1.0000x reference)
//
#include <hip/hip_runtime.h>
#include <math.h>

#define G_     128
#define E_     524288
#define EPG    4096
#define DEGMAX 48

typedef __attribute__((ext_vector_type(8))) short bf16x8;
typedef __attribute__((ext_vector_type(4))) float f32x4;
typedef __attribute__((ext_vector_type(8))) unsigned short u16x8;

__device__ inline void split_bf16(float x, short& hi, short& lo){
    unsigned u = __float_as_uint(x);
    hi = (short)(u >> 16);
    float hf = __uint_as_float(u & 0xffff0000u);
    unsigned r = __float_as_uint(x - hf);
    lo = (short)(r >> 16);
}

// ---------------- stage-1 CSR build (padded ushort rows; pads stay 0 from memset) ----------------
__global__ __launch_bounds__(256) void k_build1(const int* __restrict__ ei,
        int* __restrict__ cnt, unsigned short* __restrict__ csrcp){
    int e = blockIdx.x*256 + threadIdx.x;
    int s = ei[e], d = ei[E_ + e];
    int slot = atomicAdd(&cnt[d], 1);
    if (slot < DEGMAX) csrcp[(size_t)d*DEGMAX + slot] = (unsigned short)(s & 511);
}

// ---------------- per-graph feature prop with fused degree prop ----------------
// OUT = dinv * (sum_l A^l)(dinv * X). ushort8 octet gathers; rows zero-padded -> octet loop
// over-adds (nb*8-c) copies of y-row 0, subtracted afterwards (no tail loop).
// REGISTER HISTORY: (1024,8) forced 32 VGPR -> catastrophic spill (R7, 390 MB scratch).
// plain (1024) let compiler pick 64 VGPR for 2 blocks/CU -> still spilled ~50 MB (R9).
// (1024,4) = 1 block/CU = 128-VGPR cap -> working set (~90) fits, zero spill.
template<int NPER, int L, int IT>
__global__ __launch_bounds__(1024, 4) void k_prop(const int* __restrict__ cnt,
        const unsigned short* __restrict__ csrcp,
        const float* __restrict__ X, float* __restrict__ OUT){
    __shared__ float y[NPER*32];
    int g = blockIdx.x, fq = blockIdx.y, gbase = g*NPER;
    int t = threadIdx.x;
    int f4 = (t & 7)*4;
    int fo = fq*32 + f4;

    // ---- fused degree prop (threads t < NPER), y[0..2*NPER) ping-pong ----
    int dc = 0;
    const u16x8* dcp = nullptr;
    if (t < NPER){
        dc = min(cnt[gbase + t], DEGMAX);
        dcp = (const u16x8*)(csrcp + (size_t)(gbase + t)*DEGMAX);
        y[t] = 1.f;
    }
    __syncthreads();
    {
        float dacc = 1.f;
        int cur = 0;
        for (int l = 0; l < L; l++){
            if (t < NPER){
                const float* la = &y[cur*NPER];
                float s = 0.f;
                int nb = (dc + 7) >> 3;
                for (int jb = 0; jb < nb; jb++){
                    u16x8 oc = dcp[jb];
                    #pragma unroll
                    for (int m = 0; m < 8; m++) s += la[(int)oc[m]];
                }
                if (nb) s -= (float)(nb*8 - dc) * la[0];
                y[(1^cur)*NPER + t] = s;
                dacc += s;
            }
            __syncthreads();
            cur ^= 1;
        }
        if (t < NPER) y[2*NPER + t] = rsqrtf(fmaxf(dacc, 1e-12f));
    }
    __syncthreads();

    float4 acc[IT]; int cv[IT]; float dv[IT];
    #pragma unroll
    for (int it = 0; it < IT; it++){
        int v = (t >> 3) + 128*it;
        dv[it] = y[2*NPER + v];
        cv[it] = min(cnt[gbase + v], DEGMAX);
    }
    __syncthreads();                          // dv read before staging overwrites y
    #pragma unroll
    for (int it = 0; it < IT; it++){
        int v = (t >> 3) + 128*it;
        float d = dv[it];
        float4 w = *(const float4*)&X[(size_t)(gbase + v)*128 + fo];
        w.x*=d; w.y*=d; w.z*=d; w.w*=d;
        acc[it] = w;
        *(float4*)&y[v*32 + f4] = w;
    }
    __syncthreads();
    for (int l = 0; l < L; l++){
        float4 s[IT];
        #pragma unroll
        for (int it = 0; it < IT; it++){
            float4 ss = make_float4(0.f,0.f,0.f,0.f);
            int c = cv[it];
            int nb = (c + 7) >> 3;
            const u16x8* cp = (const u16x8*)(csrcp + (size_t)(gbase + (t >> 3) + 128*it)*DEGMAX);
            for (int jb = 0; jb < nb; jb++){
                u16x8 oc = cp[jb];
                #pragma unroll
                for (int m = 0; m < 8; m++){
                    float4 w = *(const float4*)&y[((int)oc[m])*32 + f4];
                    ss.x+=w.x; ss.y+=w.y; ss.z+=w.z; ss.w+=w.w;
                }
            }
            if (nb){
                float fp = (float)(nb*8 - c);
                float4 z = *(const float4*)&y[f4];          // row 0
                ss.x -= fp*z.x; ss.y -= fp*z.y; ss.z -= fp*z.z; ss.w -= fp*z.w;
            }
            s[it] = ss;
        }
        __syncthreads();
        #pragma unroll
        for (int it = 0; it < IT; it++){
            int v = (t >> 3) + 128*it;
            *(float4*)&y[v*32 + f4] = s[it];
            acc[it].x+=s[it].x; acc[it].y+=s[it].y; acc[it].z+=s[it].z; acc[it].w+=s[it].w;
        }
        __syncthreads();
    }
    #pragma unroll
    for (int it = 0; it < IT; it++){
        int v = (t >> 3) + 128*it;
        float d = dv[it];
        float4 w = acc[it];
        w.x*=d; w.y*=d; w.z*=d; w.w*=d;
        *(float4*)&OUT[(size_t)(gbase + v)*128 + fo] = w;
    }
}

// ---------------- split-bf16 MFMA GEMM: Y = X(Mx128) @ W(128x128) + bias ----------------
// W (hi/lo) staged once in LDS; A loaded straight to registers (no cross-wave A reuse).
template<int RT>
__global__ __launch_bounds__(256) void k_gemm_mfma(const float* __restrict__ X,
        const float* __restrict__ W, const float* __restrict__ bias, float* __restrict__ Y){
    __shared__ short wsh[128*136];
    __shared__ short wsl[128*136];
    __shared__ float bsh[128];
    int t = threadIdx.x;
    for (int e = t; e < 16384; e += 256){
        int k = e >> 7, n = e & 127;
        short hi, lo; split_bf16(W[e], hi, lo);
        wsh[n*136 + k] = hi; wsl[n*136 + k] = lo;
    }
    if (t < 128) bsh[t] = bias[t];
    __syncthreads();
    int wave = t >> 6, lane = t & 63;
    int ln = lane & 15, q = lane >> 4;
    size_t rb0 = (size_t)blockIdx.x * (64*RT);
    for (int rt = 0; rt < RT; rt++){
        size_t rb = rb0 + (size_t)rt*64;
        const float* xrow = &X[(rb + wave*16 + ln)*128 + q*8];
        f32x4 acc[8];
        #pragma unroll
        for (int i = 0; i < 8; i++) acc[i] = (f32x4){0.f,0.f,0.f,0.f};
        #pragma unroll
        for (int kc = 0; kc < 4; kc++){
            float4 xa = *(const float4*)(xrow + kc*32);
            float4 xb = *(const float4*)(xrow + kc*32 + 4);
            bf16x8 ah, al; short hi, lo;
            split_bf16(xa.x, hi, lo); ah[0]=hi; al[0]=lo;
            split_bf16(xa.y, hi, lo); ah[1]=hi; al[1]=lo;
            split_bf16(xa.z, hi, lo); ah[2]=hi; al[2]=lo;
            split_bf16(xa.w, hi, lo); ah[3]=hi; al[3]=lo;
            split_bf16(xb.x, hi, lo); ah[4]=hi; al[4]=lo;
            split_bf16(xb.y, hi, lo); ah[5]=hi; al[5]=lo;
            split_bf16(xb.z, hi, lo); ah[6]=hi; al[6]=lo;
            split_bf16(xb.w, hi, lo); ah[7]=hi; al[7]=lo;
            #pragma unroll
            for (int nt = 0; nt < 8; nt++){
                int wo = (nt*16 + ln)*136 + kc*32 + q*8;
                bf16x8 bh = *(const bf16x8*)&wsh[wo];
                bf16x8 bl = *(const bf16x8*)&wsl[wo];
                acc[nt] = __builtin_amdgcn_mfma_f32_16x16x32_bf16(ah, bh, acc[nt], 0, 0, 0);
                acc[nt] = __builtin_amdgcn_mfma_f32_16x16x32_bf16(ah, bl, acc[nt], 0, 0, 0);
                acc[nt] = __builtin_amdgcn_mfma_f32_16x16x32_bf16(al, bh, acc[nt], 0, 0, 0);
            }
        }
        #pragma unroll
        for (int nt = 0; nt < 8; nt++){
            int c = nt*16 + ln;
            float bb = bsh[c];
            #pragma unroll
            for (int r = 0; r < 4; r++){
                Y[(rb + wave*16 + q*4 + r)*128 + c] = acc[nt][r] + bb;
            }
        }
    }
}

// ---------------- fused pooling: score + top-k + scatter + edge remap + next CSR build ----------------
template<int NPER, bool BUILD>
__global__ __launch_bounds__(512) void k_pooltop(const float* __restrict__ h, const float* __restrict__ p,
        const float* __restrict__ beta, const int* __restrict__ cnt,
        const int* __restrict__ esrc_in, const int* __restrict__ edst_in,
        int* __restrict__ esrc_out, int* __restrict__ edst_out,
        int* __restrict__ cnt_next, unsigned short* __restrict__ csrcp,
        float* __restrict__ hout, int mask){
    __shared__ float q[128];
    __shared__ float sc[NPER];
    __shared__ float th[NPER];
    __shared__ int  nid[NPER];
    __shared__ float red[64];
    const int K = NPER/2;
    int g = blockIdx.x, t = threadIdx.x, gbase = g*NPER;
    float b0 = beta[0], b1 = beta[1];
    if (BUILD && t < K) cnt_next[g*K + t] = 0;
    if (t < 64){ float a = p[t], b = p[t+64]; red[t] = a*a + b*b; }
    __syncthreads();
    if (t == 0){ float s = 0.f; for (int i = 0; i < 64; i++) s += red[i]; red[0] = sqrtf(s); }
    __syncthreads();
    if (t < 128) q[t] = b0 * p[t] / red[0];
    __syncthreads();
    if (t < NPER){
        const float4* hr = (const float4*)(h + (size_t)(gbase + t)*128);
        const float4* q4 = (const float4*)q;
        float s = 0.f;
        #pragma unroll 8
        for (int j = 0; j < 32; j++){
            float4 a = hr[j], b = q4[j];
            s += a.x*b.x + a.y*b.y + a.z*b.z + a.w*b.w;
        }
        s += b1 * (float)cnt[gbase + t];
        sc[t] = s;
    }
    __syncthreads();
    if (t < NPER){
        float s = sc[t];
        int rank = 0;
        for (int j = 0; j < NPER; j++){
            float sj = sc[j];
            rank += (sj > s) || (sj == s && j < t);   // stable tie-break = lax.top_k
        }
        nid[t] = (rank < K) ? (g*K + rank) : -1;
        th[t] = tanhf(s);
    }
    __syncthreads();
    for (int base = t; base < NPER*32; base += 512){
        int v = base >> 5, f4 = base & 31;
        int ni = nid[v];
        if (ni >= 0){
            float tt = th[v];
            float4 w = *(const float4*)&h[(size_t)(gbase + v)*128 + f4*4];
            w.x*=tt; w.y*=tt; w.z*=tt; w.w*=tt;
            *(float4*)&hout[(size_t)ni*128 + f4*4] = w;
        }
    }
    if (BUILD){
        for (int i = t; i < EPG; i += 512){
            int e = g*EPG + i;
            int d = edst_in[e];
            if (d < 0) continue;
            int s_ = esrc_in[e];
            int ns = nid[s_ - gbase], nd = nid[d - gbase];
            if ((ns | nd) < 0){ edst_out[e] = -1; }
            else {
                esrc_out[e] = ns; edst_out[e] = nd;
                int slot = atomicAdd(&cnt_next[nd], 1);
                if (slot < DEGMAX) csrcp[(size_t)nd*DEGMAX + slot] = (unsigned short)(ns & mask);
            }
        }
    }
}

// ---------------- fused readout: scatter-mean + 2-layer MLP ----------------
__global__ __launch_bounds__(128) void k_meanmlp(const float* __restrict__ h, const float* __restrict__ W1,
        const float* __restrict__ b1, const float* __restrict__ W2, const float* __restrict__ b2,
        float* __restrict__ out){
    __shared__ float mr[128];
    int g = blockIdx.x, t = threadIdx.x;
    float s = 0.f;
    for (int r = 0; r < 64; r++) s += h[((size_t)g*64 + r)*128 + t];
    mr[t] = s * (1.f/64.f);
    __syncthreads();
    if (t < 64){
        float a = b1[t];
        #pragma unroll 8
        for (int k = 0; k < 128; k++) a += mr[k]*W1[k*64 + t];
        a = fmaxf(a, 0.f);
        float r = a * W2[t];
        #pragma unroll
        for (int off = 32; off > 0; off >>= 1) r += __shfl_down(r, off);
        if (t == 0) out[g] = r + b2[0];
    }
}

// ---------------- driver ----------------
extern "C" void kernel_launch(void* const* d_in, const int* in_sizes, int n_in,
                              void* d_out, int out_size, void* d_ws, size_t ws_size,
                              hipStream_t stream){
    (void)in_sizes; (void)n_in; (void)out_size; (void)ws_size;
    const float* x     = (const float*)d_in[0];
    const int*   ei    = (const int*)d_in[1];
    const float* lumpW = (const float*)d_in[3];
    const float* lumpb = (const float*)d_in[4];
    const float* convW[3]    = {(const float*)d_in[5], (const float*)d_in[7], (const float*)d_in[9]};
    const float* convB[3]    = {(const float*)d_in[6], (const float*)d_in[8], (const float*)d_in[10]};
    const float* poolP[3]    = {(const float*)d_in[11], (const float*)d_in[13], (const float*)d_in[15]};
    const float* poolBeta[3] = {(const float*)d_in[12], (const float*)d_in[14], (const float*)d_in[16]};
    const float* lin1W = (const float*)d_in[17];
    const float* lin1b = (const float*)d_in[18];
    const float* lin2W = (const float*)d_in[19];
    const float* lin2b = (const float*)d_in[20];
    float* out = (float*)d_out;

    char* w8 = (char*)d_ws;
    size_t off = 0;
    auto alloc = [&](size_t bytes)->char*{
        char* p = w8 + off; off += (bytes + 255) & ~(size_t)255; return p;
    };
    float* A     = (float*)alloc((size_t)65536*128*4);
    float* Bb    = (float*)alloc((size_t)65536*128*4);
    float* Cc    = (float*)alloc((size_t)32768*128*4);
    int*   srcA  = (int*)alloc((size_t)E_*4);
    int*   dstA  = (int*)alloc((size_t)E_*4);
    // csr1/csr2/csr3 + cnt1 contiguous: one memset zeroes rows (pad slots must be 0)
    unsigned short* csr1 = (unsigned short*)alloc((size_t)65536*DEGMAX*2);
    unsigned short* csr2 = (unsigned short*)alloc((size_t)32768*DEGMAX*2);
    unsigned short* csr3 = (unsigned short*)alloc((size_t)16384*DEGMAX*2);
    int*   cntA  = (int*)alloc((size_t)(65536+32768+16384)*4);
    int*   cnt1 = cntA, *cnt2 = cntA + 65536, *cnt3 = cntA + 98304;

    dim3 b256(256);

    size_t zbytes = (size_t)(65536+32768+16384)*DEGMAX*2 + (size_t)65536*4;
    hipMemsetAsync(csr1, 0, zbytes, stream);
    k_gemm_mfma<4><<<256, b256, 0, stream>>>(x, lumpW, lumpb, A);
    k_build1<<<E_/256, b256, 0, stream>>>(ei, cnt1, csr1);

    // ----- stage 1: conv1 (L=4, nper=512), pool -> 256/graph -----
    k_prop<512,4,4><<<dim3(G_,4), 1024, 0, stream>>>(cnt1, csr1, A, Bb);
    k_gemm_mfma<4><<<256, b256, 0, stream>>>(Bb, convW[0], convB[0], A);
    k_pooltop<512,true><<<G_, 512, 0, stream>>>(A, poolP[0], poolBeta[0], cnt1,
            ei, ei + E_, srcA, dstA, cnt2, csr2, Cc, 255);

    // ----- stage 2: conv2 (L=2, nper=256), pool -> 128/graph -----
    k_prop<256,2,2><<<dim3(G_,4), 1024, 0, stream>>>(cnt2, csr2, Cc, Bb);
    k_gemm_mfma<2><<<256, b256, 0, stream>>>(Bb, convW[1], convB[1], A);
    k_pooltop<256,true><<<G_, 512, 0, stream>>>(A, poolP[1], poolBeta[1], cnt2,
            srcA, dstA, srcA, dstA, cnt3, csr3, Cc, 127);

    // ----- stage 3: conv3 (L=2, nper=128), pool -> 64/graph -----
    k_prop<128,2,1><<<dim3(G_,4), 1024, 0, stream>>>(cnt3, csr3, Cc, Bb);
    k_gemm_mfma<1><<<256, b256, 0, stream>>>(Bb, convW[2], convB[2], A);
    k_pooltop<128,false><<<G_, 512, 0, stream>>>(A, poolP[2], poolBeta[2], cnt3,
            nullptr, nullptr, nullptr, nullptr, nullptr, nullptr, Cc, 0);

    // ----- readout -----
    k_meanmlp<<<G_, 128, 0, stream>>>(Cc, lin1W, lin1b, lin2W, lin2b, out);
}

// Round 11
// 389.347 us; speedup vs baseline: 1.0084x; 1.0084x over previous
//
#include <hip/hip_runtime.h>
#include <math.h>

#define G_     128
#define E_     524288
#define EPG    4096
#define DEGMAX 48

typedef __attribute__((ext_vector_type(8))) short bf16x8;
typedef __attribute__((ext_vector_type(4))) float f32x4;
typedef __attribute__((ext_vector_type(8))) unsigned short u16x8;

__device__ inline void split_bf16(float x, short& hi, short& lo){
    unsigned u = __float_as_uint(x);
    hi = (short)(u >> 16);
    float hf = __uint_as_float(u & 0xffff0000u);
    unsigned r = __float_as_uint(x - hf);
    lo = (short)(r >> 16);
}

// ---------------- stage-1 CSR build (padded ushort rows; pads stay 0 from memset) ----------------
__global__ __launch_bounds__(256) void k_build1(const int* __restrict__ ei,
        int* __restrict__ cnt, unsigned short* __restrict__ csrcp){
    int e = blockIdx.x*256 + threadIdx.x;
    int s = ei[e], d = ei[E_ + e];
    int slot = atomicAdd(&cnt[d], 1);
    if (slot < DEGMAX) csrcp[(size_t)d*DEGMAX + slot] = (unsigned short)(s & 511);
}

// ---------------- per-graph feature prop with fused degree prop ----------------
// OUT = dinv * (sum_l A^l)(dinv * X). ushort8 octet gathers; rows zero-padded -> octet loop
// over-adds (nb*8-c) copies of y-row 0, subtracted afterwards (no tail loop).
// REGISTER HISTORY: (1024,8) forced 32 VGPR -> catastrophic spill (R7, 390 MB scratch).
// plain (1024): compiler picked 64 VGPR for 8 waves/EU -> ~50 MB spill (R9).
// (1024,4): only a MIN hint -> compiler still chose 64 VGPR + spill (R10, 58 MB scratch).
// amdgpu_waves_per_eu(4,4) caps MAX waves/EU=4 -> allocator free to use 128 VGPR, no spill.
template<int NPER, int L, int IT>
__global__ __launch_bounds__(1024)
__attribute__((amdgpu_waves_per_eu(4, 4)))
void k_prop(const int* __restrict__ cnt,
        const unsigned short* __restrict__ csrcp,
        const float* __restrict__ X, float* __restrict__ OUT){
    __shared__ float y[NPER*32];
    int g = blockIdx.x, fq = blockIdx.y, gbase = g*NPER;
    int t = threadIdx.x;
    int f4 = (t & 7)*4;
    int fo = fq*32 + f4;

    // ---- fused degree prop (threads t < NPER), y[0..2*NPER) ping-pong ----
    int dc = 0;
    const u16x8* dcp = nullptr;
    if (t < NPER){
        dc = min(cnt[gbase + t], DEGMAX);
        dcp = (const u16x8*)(csrcp + (size_t)(gbase + t)*DEGMAX);
        y[t] = 1.f;
    }
    __syncthreads();
    {
        float dacc = 1.f;
        int cur = 0;
        for (int l = 0; l < L; l++){
            if (t < NPER){
                const float* la = &y[cur*NPER];
                float s = 0.f;
                int nb = (dc + 7) >> 3;
                for (int jb = 0; jb < nb; jb++){
                    u16x8 oc = dcp[jb];
                    #pragma unroll
                    for (int m = 0; m < 8; m++) s += la[(int)oc[m]];
                }
                if (nb) s -= (float)(nb*8 - dc) * la[0];
                y[(1^cur)*NPER + t] = s;
                dacc += s;
            }
            __syncthreads();
            cur ^= 1;
        }
        if (t < NPER) y[2*NPER + t] = rsqrtf(fmaxf(dacc, 1e-12f));
    }
    __syncthreads();

    float4 acc[IT]; int cv[IT]; float dv[IT];
    #pragma unroll
    for (int it = 0; it < IT; it++){
        int v = (t >> 3) + 128*it;
        dv[it] = y[2*NPER + v];
        cv[it] = min(cnt[gbase + v], DEGMAX);
    }
    __syncthreads();                          // dv read before staging overwrites y
    #pragma unroll
    for (int it = 0; it < IT; it++){
        int v = (t >> 3) + 128*it;
        float d = dv[it];
        float4 w = *(const float4*)&X[(size_t)(gbase + v)*128 + fo];
        w.x*=d; w.y*=d; w.z*=d; w.w*=d;
        acc[it] = w;
        *(float4*)&y[v*32 + f4] = w;
    }
    __syncthreads();
    for (int l = 0; l < L; l++){
        float4 s[IT];
        #pragma unroll
        for (int it = 0; it < IT; it++){
            float4 ss = make_float4(0.f,0.f,0.f,0.f);
            int c = cv[it];
            int nb = (c + 7) >> 3;
            const u16x8* cp = (const u16x8*)(csrcp + (size_t)(gbase + (t >> 3) + 128*it)*DEGMAX);
            for (int jb = 0; jb < nb; jb++){
                u16x8 oc = cp[jb];
                #pragma unroll
                for (int m = 0; m < 8; m++){
                    float4 w = *(const float4*)&y[((int)oc[m])*32 + f4];
                    ss.x+=w.x; ss.y+=w.y; ss.z+=w.z; ss.w+=w.w;
                }
            }
            if (nb){
                float fp = (float)(nb*8 - c);
                float4 z = *(const float4*)&y[f4];          // row 0
                ss.x -= fp*z.x; ss.y -= fp*z.y; ss.z -= fp*z.z; ss.w -= fp*z.w;
            }
            s[it] = ss;
        }
        __syncthreads();
        #pragma unroll
        for (int it = 0; it < IT; it++){
            int v = (t >> 3) + 128*it;
            *(float4*)&y[v*32 + f4] = s[it];
            acc[it].x+=s[it].x; acc[it].y+=s[it].y; acc[it].z+=s[it].z; acc[it].w+=s[it].w;
        }
        __syncthreads();
    }
    #pragma unroll
    for (int it = 0; it < IT; it++){
        int v = (t >> 3) + 128*it;
        float d = dv[it];
        float4 w = acc[it];
        w.x*=d; w.y*=d; w.z*=d; w.w*=d;
        *(float4*)&OUT[(size_t)(gbase + v)*128 + fo] = w;
    }
}

// ---------------- split-bf16 MFMA GEMM: Y = X(Mx128) @ W(128x128) + bias ----------------
// W (hi/lo) staged once in LDS; A loaded straight to registers (no cross-wave A reuse).
template<int RT>
__global__ __launch_bounds__(256) void k_gemm_mfma(const float* __restrict__ X,
        const float* __restrict__ W, const float* __restrict__ bias, float* __restrict__ Y){
    __shared__ short wsh[128*136];
    __shared__ short wsl[128*136];
    __shared__ float bsh[128];
    int t = threadIdx.x;
    for (int e = t; e < 16384; e += 256){
        int k = e >> 7, n = e & 127;
        short hi, lo; split_bf16(W[e], hi, lo);
        wsh[n*136 + k] = hi; wsl[n*136 + k] = lo;
    }
    if (t < 128) bsh[t] = bias[t];
    __syncthreads();
    int wave = t >> 6, lane = t & 63;
    int ln = lane & 15, q = lane >> 4;
    size_t rb0 = (size_t)blockIdx.x * (64*RT);
    for (int rt = 0; rt < RT; rt++){
        size_t rb = rb0 + (size_t)rt*64;
        const float* xrow = &X[(rb + wave*16 + ln)*128 + q*8];
        f32x4 acc[8];
        #pragma unroll
        for (int i = 0; i < 8; i++) acc[i] = (f32x4){0.f,0.f,0.f,0.f};
        #pragma unroll
        for (int kc = 0; kc < 4; kc++){
            float4 xa = *(const float4*)(xrow + kc*32);
            float4 xb = *(const float4*)(xrow + kc*32 + 4);
            bf16x8 ah, al; short hi, lo;
            split_bf16(xa.x, hi, lo); ah[0]=hi; al[0]=lo;
            split_bf16(xa.y, hi, lo); ah[1]=hi; al[1]=lo;
            split_bf16(xa.z, hi, lo); ah[2]=hi; al[2]=lo;
            split_bf16(xa.w, hi, lo); ah[3]=hi; al[3]=lo;
            split_bf16(xb.x, hi, lo); ah[4]=hi; al[4]=lo;
            split_bf16(xb.y, hi, lo); ah[5]=hi; al[5]=lo;
            split_bf16(xb.z, hi, lo); ah[6]=hi; al[6]=lo;
            split_bf16(xb.w, hi, lo); ah[7]=hi; al[7]=lo;
            #pragma unroll
            for (int nt = 0; nt < 8; nt++){
                int wo = (nt*16 + ln)*136 + kc*32 + q*8;
                bf16x8 bh = *(const bf16x8*)&wsh[wo];
                bf16x8 bl = *(const bf16x8*)&wsl[wo];
                acc[nt] = __builtin_amdgcn_mfma_f32_16x16x32_bf16(ah, bh, acc[nt], 0, 0, 0);
                acc[nt] = __builtin_amdgcn_mfma_f32_16x16x32_bf16(ah, bl, acc[nt], 0, 0, 0);
                acc[nt] = __builtin_amdgcn_mfma_f32_16x16x32_bf16(al, bh, acc[nt], 0, 0, 0);
            }
        }
        #pragma unroll
        for (int nt = 0; nt < 8; nt++){
            int c = nt*16 + ln;
            float bb = bsh[c];
            #pragma unroll
            for (int r = 0; r < 4; r++){
                Y[(rb + wave*16 + q*4 + r)*128 + c] = acc[nt][r] + bb;
            }
        }
    }
}

// ---------------- fused pooling: score + top-k + scatter + edge remap + next CSR build ----------------
template<int NPER, bool BUILD>
__global__ __launch_bounds__(512) void k_pooltop(const float* __restrict__ h, const float* __restrict__ p,
        const float* __restrict__ beta, const int* __restrict__ cnt,
        const int* __restrict__ esrc_in, const int* __restrict__ edst_in,
        int* __restrict__ esrc_out, int* __restrict__ edst_out,
        int* __restrict__ cnt_next, unsigned short* __restrict__ csrcp,
        float* __restrict__ hout, int mask){
    __shared__ float q[128];
    __shared__ float sc[NPER];
    __shared__ float th[NPER];
    __shared__ int  nid[NPER];
    __shared__ float red[64];
    const int K = NPER/2;
    int g = blockIdx.x, t = threadIdx.x, gbase = g*NPER;
    float b0 = beta[0], b1 = beta[1];
    if (BUILD && t < K) cnt_next[g*K + t] = 0;
    if (t < 64){ float a = p[t], b = p[t+64]; red[t] = a*a + b*b; }
    __syncthreads();
    if (t == 0){ float s = 0.f; for (int i = 0; i < 64; i++) s += red[i]; red[0] = sqrtf(s); }
    __syncthreads();
    if (t < 128) q[t] = b0 * p[t] / red[0];
    __syncthreads();
    if (t < NPER){
        const float4* hr = (const float4*)(h + (size_t)(gbase + t)*128);
        const float4* q4 = (const float4*)q;
        float s = 0.f;
        #pragma unroll 8
        for (int j = 0; j < 32; j++){
            float4 a = hr[j], b = q4[j];
            s += a.x*b.x + a.y*b.y + a.z*b.z + a.w*b.w;
        }
        s += b1 * (float)cnt[gbase + t];
        sc[t] = s;
    }
    __syncthreads();
    if (t < NPER){
        float s = sc[t];
        int rank = 0;
        for (int j = 0; j < NPER; j++){
            float sj = sc[j];
            rank += (sj > s) || (sj == s && j < t);   // stable tie-break = lax.top_k
        }
        nid[t] = (rank < K) ? (g*K + rank) : -1;
        th[t] = tanhf(s);
    }
    __syncthreads();
    for (int base = t; base < NPER*32; base += 512){
        int v = base >> 5, f4 = base & 31;
        int ni = nid[v];
        if (ni >= 0){
            float tt = th[v];
            float4 w = *(const float4*)&h[(size_t)(gbase + v)*128 + f4*4];
            w.x*=tt; w.y*=tt; w.z*=tt; w.w*=tt;
            *(float4*)&hout[(size_t)ni*128 + f4*4] = w;
        }
    }
    if (BUILD){
        for (int i = t; i < EPG; i += 512){
            int e = g*EPG + i;
            int d = edst_in[e];
            if (d < 0) continue;
            int s_ = esrc_in[e];
            int ns = nid[s_ - gbase], nd = nid[d - gbase];
            if ((ns | nd) < 0){ edst_out[e] = -1; }
            else {
                esrc_out[e] = ns; edst_out[e] = nd;
                int slot = atomicAdd(&cnt_next[nd], 1);
                if (slot < DEGMAX) csrcp[(size_t)nd*DEGMAX + slot] = (unsigned short)(ns & mask);
            }
        }
    }
}

// ---------------- fused readout: scatter-mean + 2-layer MLP ----------------
__global__ __launch_bounds__(128) void k_meanmlp(const float* __restrict__ h, const float* __restrict__ W1,
        const float* __restrict__ b1, const float* __restrict__ W2, const float* __restrict__ b2,
        float* __restrict__ out){
    __shared__ float mr[128];
    int g = blockIdx.x, t = threadIdx.x;
    float s = 0.f;
    for (int r = 0; r < 64; r++) s += h[((size_t)g*64 + r)*128 + t];
    mr[t] = s * (1.f/64.f);
    __syncthreads();
    if (t < 64){
        float a = b1[t];
        #pragma unroll 8
        for (int k = 0; k < 128; k++) a += mr[k]*W1[k*64 + t];
        a = fmaxf(a, 0.f);
        float r = a * W2[t];
        #pragma unroll
        for (int off = 32; off > 0; off >>= 1) r += __shfl_down(r, off);
        if (t == 0) out[g] = r + b2[0];
    }
}

// ---------------- driver ----------------
extern "C" void kernel_launch(void* const* d_in, const int* in_sizes, int n_in,
                              void* d_out, int out_size, void* d_ws, size_t ws_size,
                              hipStream_t stream){
    (void)in_sizes; (void)n_in; (void)out_size; (void)ws_size;
    const float* x     = (const float*)d_in[0];
    const int*   ei    = (const int*)d_in[1];
    const float* lumpW = (const float*)d_in[3];
    const float* lumpb = (const float*)d_in[4];
    const float* convW[3]    = {(const float*)d_in[5], (const float*)d_in[7], (const float*)d_in[9]};
    const float* convB[3]    = {(const float*)d_in[6], (const float*)d_in[8], (const float*)d_in[10]};
    const float* poolP[3]    = {(const float*)d_in[11], (const float*)d_in[13], (const float*)d_in[15]};
    const float* poolBeta[3] = {(const float*)d_in[12], (const float*)d_in[14], (const float*)d_in[16]};
    const float* lin1W = (const float*)d_in[17];
    const float* lin1b = (const float*)d_in[18];
    const float* lin2W = (const float*)d_in[19];
    const float* lin2b = (const float*)d_in[20];
    float* out = (float*)d_out;

    char* w8 = (char*)d_ws;
    size_t off = 0;
    auto alloc = [&](size_t bytes)->char*{
        char* p = w8 + off; off += (bytes + 255) & ~(size_t)255; return p;
    };
    float* A     = (float*)alloc((size_t)65536*128*4);
    float* Bb    = (float*)alloc((size_t)65536*128*4);
    float* Cc    = (float*)alloc((size_t)32768*128*4);
    int*   srcA  = (int*)alloc((size_t)E_*4);
    int*   dstA  = (int*)alloc((size_t)E_*4);
    // csr1/csr2/csr3 + cnt1 contiguous: one memset zeroes rows (pad slots must be 0)
    unsigned short* csr1 = (unsigned short*)alloc((size_t)65536*DEGMAX*2);
    unsigned short* csr2 = (unsigned short*)alloc((size_t)32768*DEGMAX*2);
    unsigned short* csr3 = (unsigned short*)alloc((size_t)16384*DEGMAX*2);
    int*   cntA  = (int*)alloc((size_t)(65536+32768+16384)*4);
    int*   cnt1 = cntA, *cnt2 = cntA + 65536, *cnt3 = cntA + 98304;

    dim3 b256(256);

    size_t zbytes = (size_t)(65536+32768+16384)*DEGMAX*2 + (size_t)65536*4;
    hipMemsetAsync(csr1, 0, zbytes, stream);
    k_gemm_mfma<4><<<256, b256, 0, stream>>>(x, lumpW, lumpb, A);
    k_build1<<<E_/256, b256, 0, stream>>>(ei, cnt1, csr1);

    // ----- stage 1: conv1 (L=4, nper=512), pool -> 256/graph -----
    k_prop<512,4,4><<<dim3(G_,4), 1024, 0, stream>>>(cnt1, csr1, A, Bb);
    k_gemm_mfma<4><<<256, b256, 0, stream>>>(Bb, convW[0], convB[0], A);
    k_pooltop<512,true><<<G_, 512, 0, stream>>>(A, poolP[0], poolBeta[0], cnt1,
            ei, ei + E_, srcA, dstA, cnt2, csr2, Cc, 255);

    // ----- stage 2: conv2 (L=2, nper=256), pool -> 128/graph -----
    k_prop<256,2,2><<<dim3(G_,4), 1024, 0, stream>>>(cnt2, csr2, Cc, Bb);
    k_gemm_mfma<2><<<256, b256, 0, stream>>>(Bb, convW[1], convB[1], A);
    k_pooltop<256,true><<<G_, 512, 0, stream>>>(A, poolP[1], poolBeta[1], cnt2,
            srcA, dstA, srcA, dstA, cnt3, csr3, Cc, 127);

    // ----- stage 3: conv3 (L=2, nper=128), pool -> 64/graph -----
    k_prop<128,2,1><<<dim3(G_,4), 1024, 0, stream>>>(cnt3, csr3, Cc, Bb);
    k_gemm_mfma<1><<<256, b256, 0, stream>>>(Bb, convW[2], convB[2], A);
    k_pooltop<128,false><<<G_, 512, 0, stream>>>(A, poolP[2], poolBeta[2], cnt3,
            nullptr, nullptr, nullptr, nullptr, nullptr, nullptr, Cc, 0);

    // ----- readout -----
    k_meanmlp<<<G_, 128, 0, stream>>>(Cc, lin1W, lin1b, lin2W, lin2b, out);
}

// Round 12
// 357.996 us; speedup vs baseline: 1.0967x; 1.0876x over previous
//
#include <hip/hip_runtime.h>
#include <math.h>

#define G_     128
#define E_     524288
#define EPG    4096
#define DEGMAX 48

typedef __attribute__((ext_vector_type(8))) short bf16x8;
typedef __attribute__((ext_vector_type(4))) float f32x4;
typedef __attribute__((ext_vector_type(4))) unsigned short u16x4;

__device__ inline void split_bf16(float x, short& hi, short& lo){
    unsigned u = __float_as_uint(x);
    hi = (short)(u >> 16);
    float hf = __uint_as_float(u & 0xffff0000u);
    unsigned r = __float_as_uint(x - hf);
    lo = (short)(r >> 16);
}

// ---------------- stage-1 CSR build (padded ushort rows; pads stay 0 from memset) ----------------
__global__ __launch_bounds__(256) void k_build1(const int* __restrict__ ei,
        int* __restrict__ cnt, unsigned short* __restrict__ csrcp){
    int e = blockIdx.x*256 + threadIdx.x;
    int s = ei[e], d = ei[E_ + e];
    int slot = atomicAdd(&cnt[d], 1);
    if (slot < DEGMAX) csrcp[(size_t)d*DEGMAX + slot] = (unsigned short)(s & 511);
}

// ---------------- per-graph feature prop with fused degree prop ----------------
// OUT = dinv * (sum_l A^l)(dinv * X). QUAD (u16x4) gathers, unroll 1: transient regs
// ~18 (4 float4 in flight + idx) so peak pressure fits 64 VGPRs without spill.
// REGISTER HISTORY: octet gathers (8 float4 in flight) spilled ~58 MB/dispatch at the
// compiler's chosen 64-VGPR budget (R9-R11, WRITE_SIZE 92 MB vs 33.5 MB OUT);
// (1024,8) forced 32 VGPR = catastrophic spill (R7). Attributes did not unpin 64.
template<int NPER, int L, int IT>
__global__ __launch_bounds__(1024)
__attribute__((amdgpu_waves_per_eu(4, 4)))
void k_prop(const int* __restrict__ cnt,
        const unsigned short* __restrict__ csrcp,
        const float* __restrict__ X, float* __restrict__ OUT){
    __shared__ float y[NPER*32];
    int g = blockIdx.x, fq = blockIdx.y, gbase = g*NPER;
    int t = threadIdx.x;
    int f4 = (t & 7)*4;
    int fo = fq*32 + f4;

    // ---- fused degree prop (threads t < NPER), y[0..2*NPER) ping-pong ----
    int dc = 0;
    if (t < NPER){
        dc = min(cnt[gbase + t], DEGMAX);
        y[t] = 1.f;
    }
    __syncthreads();
    {
        float dacc = 1.f;
        int cur = 0;
        for (int l = 0; l < L; l++){
            if (t < NPER){
                const float* la = &y[cur*NPER];
                float s = 0.f;
                int nq = (dc + 3) >> 2;
                const u16x4* cp = (const u16x4*)(csrcp + (size_t)(gbase + t)*DEGMAX);
                #pragma unroll 1
                for (int jq = 0; jq < nq; jq++){
                    u16x4 oc = cp[jq];
                    s += (la[(int)oc[0]] + la[(int)oc[1]]) + (la[(int)oc[2]] + la[(int)oc[3]]);
                }
                if (nq) s -= (float)(nq*4 - dc) * la[0];
                y[(1^cur)*NPER + t] = s;
                dacc += s;
            }
            __syncthreads();
            cur ^= 1;
        }
        if (t < NPER) y[2*NPER + t] = rsqrtf(fmaxf(dacc, 1e-12f));
    }
    __syncthreads();

    float4 acc[IT]; int cv[IT]; float dv[IT];
    #pragma unroll
    for (int it = 0; it < IT; it++){
        int v = (t >> 3) + 128*it;
        dv[it] = y[2*NPER + v];
        cv[it] = min(cnt[gbase + v], DEGMAX);
    }
    __syncthreads();                          // dv read before staging overwrites y
    #pragma unroll
    for (int it = 0; it < IT; it++){
        int v = (t >> 3) + 128*it;
        float d = dv[it];
        float4 w = *(const float4*)&X[(size_t)(gbase + v)*128 + fo];
        w.x*=d; w.y*=d; w.z*=d; w.w*=d;
        acc[it] = w;
        *(float4*)&y[v*32 + f4] = w;
    }
    __syncthreads();
    for (int l = 0; l < L; l++){
        float4 s[IT];
        #pragma unroll
        for (int it = 0; it < IT; it++){
            float4 ss = make_float4(0.f,0.f,0.f,0.f);
            int c = cv[it];
            int nq = (c + 3) >> 2;
            const u16x4* cp = (const u16x4*)(csrcp + (size_t)(gbase + (t >> 3) + 128*it)*DEGMAX);
            #pragma unroll 1
            for (int jq = 0; jq < nq; jq++){
                u16x4 oc = cp[jq];
                float4 w0 = *(const float4*)&y[((int)oc[0])*32 + f4];
                float4 w1 = *(const float4*)&y[((int)oc[1])*32 + f4];
                float4 w2 = *(const float4*)&y[((int)oc[2])*32 + f4];
                float4 w3 = *(const float4*)&y[((int)oc[3])*32 + f4];
                ss.x += (w0.x + w1.x) + (w2.x + w3.x);
                ss.y += (w0.y + w1.y) + (w2.y + w3.y);
                ss.z += (w0.z + w1.z) + (w2.z + w3.z);
                ss.w += (w0.w + w1.w) + (w2.w + w3.w);
            }
            if (nq){
                float fp = (float)(nq*4 - c);
                float4 z = *(const float4*)&y[f4];          // row 0
                ss.x -= fp*z.x; ss.y -= fp*z.y; ss.z -= fp*z.z; ss.w -= fp*z.w;
            }
            s[it] = ss;
        }
        __syncthreads();
        #pragma unroll
        for (int it = 0; it < IT; it++){
            int v = (t >> 3) + 128*it;
            *(float4*)&y[v*32 + f4] = s[it];
            acc[it].x+=s[it].x; acc[it].y+=s[it].y; acc[it].z+=s[it].z; acc[it].w+=s[it].w;
        }
        __syncthreads();
    }
    #pragma unroll
    for (int it = 0; it < IT; it++){
        int v = (t >> 3) + 128*it;
        float d = dv[it];
        float4 w = acc[it];
        w.x*=d; w.y*=d; w.z*=d; w.w*=d;
        *(float4*)&OUT[(size_t)(gbase + v)*128 + fo] = w;
    }
}

// ---------------- split-bf16 MFMA GEMM: Y = X(Mx128) @ W(128x128) + bias ----------------
// W (hi/lo) staged once in LDS; A loaded straight to registers (no cross-wave A reuse).
template<int RT>
__global__ __launch_bounds__(256) void k_gemm_mfma(const float* __restrict__ X,
        const float* __restrict__ W, const float* __restrict__ bias, float* __restrict__ Y){
    __shared__ short wsh[128*136];
    __shared__ short wsl[128*136];
    __shared__ float bsh[128];
    int t = threadIdx.x;
    for (int e = t; e < 16384; e += 256){
        int k = e >> 7, n = e & 127;
        short hi, lo; split_bf16(W[e], hi, lo);
        wsh[n*136 + k] = hi; wsl[n*136 + k] = lo;
    }
    if (t < 128) bsh[t] = bias[t];
    __syncthreads();
    int wave = t >> 6, lane = t & 63;
    int ln = lane & 15, q = lane >> 4;
    size_t rb0 = (size_t)blockIdx.x * (64*RT);
    for (int rt = 0; rt < RT; rt++){
        size_t rb = rb0 + (size_t)rt*64;
        const float* xrow = &X[(rb + wave*16 + ln)*128 + q*8];
        f32x4 acc[8];
        #pragma unroll
        for (int i = 0; i < 8; i++) acc[i] = (f32x4){0.f,0.f,0.f,0.f};
        #pragma unroll
        for (int kc = 0; kc < 4; kc++){
            float4 xa = *(const float4*)(xrow + kc*32);
            float4 xb = *(const float4*)(xrow + kc*32 + 4);
            bf16x8 ah, al; short hi, lo;
            split_bf16(xa.x, hi, lo); ah[0]=hi; al[0]=lo;
            split_bf16(xa.y, hi, lo); ah[1]=hi; al[1]=lo;
            split_bf16(xa.z, hi, lo); ah[2]=hi; al[2]=lo;
            split_bf16(xa.w, hi, lo); ah[3]=hi; al[3]=lo;
            split_bf16(xb.x, hi, lo); ah[4]=hi; al[4]=lo;
            split_bf16(xb.y, hi, lo); ah[5]=hi; al[5]=lo;
            split_bf16(xb.z, hi, lo); ah[6]=hi; al[6]=lo;
            split_bf16(xb.w, hi, lo); ah[7]=hi; al[7]=lo;
            #pragma unroll
            for (int nt = 0; nt < 8; nt++){
                int wo = (nt*16 + ln)*136 + kc*32 + q*8;
                bf16x8 bh = *(const bf16x8*)&wsh[wo];
                bf16x8 bl = *(const bf16x8*)&wsl[wo];
                acc[nt] = __builtin_amdgcn_mfma_f32_16x16x32_bf16(ah, bh, acc[nt], 0, 0, 0);
                acc[nt] = __builtin_amdgcn_mfma_f32_16x16x32_bf16(ah, bl, acc[nt], 0, 0, 0);
                acc[nt] = __builtin_amdgcn_mfma_f32_16x16x32_bf16(al, bh, acc[nt], 0, 0, 0);
            }
        }
        #pragma unroll
        for (int nt = 0; nt < 8; nt++){
            int c = nt*16 + ln;
            float bb = bsh[c];
            #pragma unroll
            for (int r = 0; r < 4; r++){
                Y[(rb + wave*16 + q*4 + r)*128 + c] = acc[nt][r] + bb;
            }
        }
    }
}

// ---------------- fused pooling: score + top-k + scatter + edge remap + next CSR build ----------------
template<int NPER, bool BUILD>
__global__ __launch_bounds__(512) void k_pooltop(const float* __restrict__ h, const float* __restrict__ p,
        const float* __restrict__ beta, const int* __restrict__ cnt,
        const int* __restrict__ esrc_in, const int* __restrict__ edst_in,
        int* __restrict__ esrc_out, int* __restrict__ edst_out,
        int* __restrict__ cnt_next, unsigned short* __restrict__ csrcp,
        float* __restrict__ hout, int mask){
    __shared__ float q[128];
    __shared__ float sc[NPER];
    __shared__ float th[NPER];
    __shared__ int  nid[NPER];
    __shared__ float red[64];
    const int K = NPER/2;
    int g = blockIdx.x, t = threadIdx.x, gbase = g*NPER;
    float b0 = beta[0], b1 = beta[1];
    if (BUILD && t < K) cnt_next[g*K + t] = 0;
    if (t < 64){ float a = p[t], b = p[t+64]; red[t] = a*a + b*b; }
    __syncthreads();
    if (t == 0){ float s = 0.f; for (int i = 0; i < 64; i++) s += red[i]; red[0] = sqrtf(s); }
    __syncthreads();
    if (t < 128) q[t] = b0 * p[t] / red[0];
    __syncthreads();
    if (t < NPER){
        const float4* hr = (const float4*)(h + (size_t)(gbase + t)*128);
        const float4* q4 = (const float4*)q;
        float s = 0.f;
        #pragma unroll 8
        for (int j = 0; j < 32; j++){
            float4 a = hr[j], b = q4[j];
            s += a.x*b.x + a.y*b.y + a.z*b.z + a.w*b.w;
        }
        s += b1 * (float)cnt[gbase + t];
        sc[t] = s;
    }
    __syncthreads();
    if (t < NPER){
        float s = sc[t];
        int rank = 0;
        for (int j = 0; j < NPER; j++){
            float sj = sc[j];
            rank += (sj > s) || (sj == s && j < t);   // stable tie-break = lax.top_k
        }
        nid[t] = (rank < K) ? (g*K + rank) : -1;
        th[t] = tanhf(s);
    }
    __syncthreads();
    for (int base = t; base < NPER*32; base += 512){
        int v = base >> 5, f4 = base & 31;
        int ni = nid[v];
        if (ni >= 0){
            float tt = th[v];
            float4 w = *(const float4*)&h[(size_t)(gbase + v)*128 + f4*4];
            w.x*=tt; w.y*=tt; w.z*=tt; w.w*=tt;
            *(float4*)&hout[(size_t)ni*128 + f4*4] = w;
        }
    }
    if (BUILD){
        for (int i = t; i < EPG; i += 512){
            int e = g*EPG + i;
            int d = edst_in[e];
            if (d < 0) continue;
            int s_ = esrc_in[e];
            int ns = nid[s_ - gbase], nd = nid[d - gbase];
            if ((ns | nd) < 0){ edst_out[e] = -1; }
            else {
                esrc_out[e] = ns; edst_out[e] = nd;
                int slot = atomicAdd(&cnt_next[nd], 1);
                if (slot < DEGMAX) csrcp[(size_t)nd*DEGMAX + slot] = (unsigned short)(ns & mask);
            }
        }
    }
}

// ---------------- fused readout: scatter-mean + 2-layer MLP ----------------
__global__ __launch_bounds__(128) void k_meanmlp(const float* __restrict__ h, const float* __restrict__ W1,
        const float* __restrict__ b1, const float* __restrict__ W2, const float* __restrict__ b2,
        float* __restrict__ out){
    __shared__ float mr[128];
    int g = blockIdx.x, t = threadIdx.x;
    float s = 0.f;
    for (int r = 0; r < 64; r++) s += h[((size_t)g*64 + r)*128 + t];
    mr[t] = s * (1.f/64.f);
    __syncthreads();
    if (t < 64){
        float a = b1[t];
        #pragma unroll 8
        for (int k = 0; k < 128; k++) a += mr[k]*W1[k*64 + t];
        a = fmaxf(a, 0.f);
        float r = a * W2[t];
        #pragma unroll
        for (int off = 32; off > 0; off >>= 1) r += __shfl_down(r, off);
        if (t == 0) out[g] = r + b2[0];
    }
}

// ---------------- driver ----------------
extern "C" void kernel_launch(void* const* d_in, const int* in_sizes, int n_in,
                              void* d_out, int out_size, void* d_ws, size_t ws_size,
                              hipStream_t stream){
    (void)in_sizes; (void)n_in; (void)out_size; (void)ws_size;
    const float* x     = (const float*)d_in[0];
    const int*   ei    = (const int*)d_in[1];
    const float* lumpW = (const float*)d_in[3];
    const float* lumpb = (const float*)d_in[4];
    const float* convW[3]    = {(const float*)d_in[5], (const float*)d_in[7], (const float*)d_in[9]};
    const float* convB[3]    = {(const float*)d_in[6], (const float*)d_in[8], (const float*)d_in[10]};
    const float* poolP[3]    = {(const float*)d_in[11], (const float*)d_in[13], (const float*)d_in[15]};
    const float* poolBeta[3] = {(const float*)d_in[12], (const float*)d_in[14], (const float*)d_in[16]};
    const float* lin1W = (const float*)d_in[17];
    const float* lin1b = (const float*)d_in[18];
    const float* lin2W = (const float*)d_in[19];
    const float* lin2b = (const float*)d_in[20];
    float* out = (float*)d_out;

    char* w8 = (char*)d_ws;
    size_t off = 0;
    auto alloc = [&](size_t bytes)->char*{
        char* p = w8 + off; off += (bytes + 255) & ~(size_t)255; return p;
    };
    float* A     = (float*)alloc((size_t)65536*128*4);
    float* Bb    = (float*)alloc((size_t)65536*128*4);
    float* Cc    = (float*)alloc((size_t)32768*128*4);
    int*   srcA  = (int*)alloc((size_t)E_*4);
    int*   dstA  = (int*)alloc((size_t)E_*4);
    // csr1/csr2/csr3 + cnt1 contiguous: one memset zeroes rows (pad slots must be 0)
    unsigned short* csr1 = (unsigned short*)alloc((size_t)65536*DEGMAX*2);
    unsigned short* csr2 = (unsigned short*)alloc((size_t)32768*DEGMAX*2);
    unsigned short* csr3 = (unsigned short*)alloc((size_t)16384*DEGMAX*2);
    int*   cntA  = (int*)alloc((size_t)(65536+32768+16384)*4);
    int*   cnt1 = cntA, *cnt2 = cntA + 65536, *cnt3 = cntA + 98304;

    dim3 b256(256);

    size_t zbytes = (size_t)(65536+32768+16384)*DEGMAX*2 + (size_t)65536*4;
    hipMemsetAsync(csr1, 0, zbytes, stream);
    k_gemm_mfma<4><<<256, b256, 0, stream>>>(x, lumpW, lumpb, A);
    k_build1<<<E_/256, b256, 0, stream>>>(ei, cnt1, csr1);

    // ----- stage 1: conv1 (L=4, nper=512), pool -> 256/graph -----
    k_prop<512,4,4><<<dim3(G_,4), 1024, 0, stream>>>(cnt1, csr1, A, Bb);
    k_gemm_mfma<4><<<256, b256, 0, stream>>>(Bb, convW[0], convB[0], A);
    k_pooltop<512,true><<<G_, 512, 0, stream>>>(A, poolP[0], poolBeta[0], cnt1,
            ei, ei + E_, srcA, dstA, cnt2, csr2, Cc, 255);

    // ----- stage 2: conv2 (L=2, nper=256), pool -> 128/graph -----
    k_prop<256,2,2><<<dim3(G_,4), 1024, 0, stream>>>(cnt2, csr2, Cc, Bb);
    k_gemm_mfma<2><<<256, b256, 0, stream>>>(Bb, convW[1], convB[1], A);
    k_pooltop<256,true><<<G_, 512, 0, stream>>>(A, poolP[1], poolBeta[1], cnt2,
            srcA, dstA, srcA, dstA, cnt3, csr3, Cc, 127);

    // ----- stage 3: conv3 (L=2, nper=128), pool -> 64/graph -----
    k_prop<128,2,1><<<dim3(G_,4), 1024, 0, stream>>>(cnt3, csr3, Cc, Bb);
    k_gemm_mfma<1><<<256, b256, 0, stream>>>(Bb, convW[2], convB[2], A);
    k_pooltop<128,false><<<G_, 512, 0, stream>>>(A, poolP[2], poolBeta[2], cnt3,
            nullptr, nullptr, nullptr, nullptr, nullptr, nullptr, Cc, 0);

    // ----- readout -----
    k_meanmlp<<<G_, 128, 0, stream>>>(Cc, lin1W, lin1b, lin2W, lin2b, out);
}

// Round 13
// 352.816 us; speedup vs baseline: 1.1128x; 1.0147x over previous
//
#include <hip/hip_runtime.h>
#include <math.h>

#define G_     128
#define E_     524288
#define EPG    4096
#define DEGMAX 48

typedef __attribute__((ext_vector_type(8))) short bf16x8;
typedef __attribute__((ext_vector_type(4))) float f32x4;
typedef __attribute__((ext_vector_type(4))) unsigned short u16x4;

__device__ inline void split_bf16(float x, short& hi, short& lo){
    unsigned u = __float_as_uint(x);
    hi = (short)(u >> 16);
    float hf = __uint_as_float(u & 0xffff0000u);
    unsigned r = __float_as_uint(x - hf);
    lo = (short)(r >> 16);
}

// ---------------- stage-1 CSR build (padded ushort rows; pads stay 0 from memset) ----------------
__global__ __launch_bounds__(256) void k_build1(const int* __restrict__ ei,
        int* __restrict__ cnt, unsigned short* __restrict__ csrcp){
    int e = blockIdx.x*256 + threadIdx.x;
    int s = ei[e], d = ei[E_ + e];
    int slot = atomicAdd(&cnt[d], 1);
    if (slot < DEGMAX) csrcp[(size_t)d*DEGMAX + slot] = (unsigned short)(s & 511);
}

// ---------------- per-graph feature prop with fused degree prop ----------------
// OUT = dinv * (sum_l A^l)(dinv * X). QUAD (u16x4) gathers, unroll 1: peak register
// pressure fits the compiler's natural <=64 budget (R12: VGPR=60, WRITE_SIZE == OUT, no spill).
// REGISTER HISTORY: octet gathers spilled ~58 MB at 64 VGPR (R9-R11); (1024,8) forced
// 32 VGPR = catastrophic spill (R7). R12's waves_per_eu(4,4) capped HW at 1 block/CU
// (occupancy 37%) while regs fit 60 -> cap removed R13 to allow 2 blocks/CU.
template<int NPER, int L, int IT>
__global__ __launch_bounds__(1024)
void k_prop(const int* __restrict__ cnt,
        const unsigned short* __restrict__ csrcp,
        const float* __restrict__ X, float* __restrict__ OUT){
    __shared__ float y[NPER*32];
    int g = blockIdx.x, fq = blockIdx.y, gbase = g*NPER;
    int t = threadIdx.x;
    int f4 = (t & 7)*4;
    int fo = fq*32 + f4;

    // ---- fused degree prop (threads t < NPER), y[0..2*NPER) ping-pong ----
    int dc = 0;
    if (t < NPER){
        dc = min(cnt[gbase + t], DEGMAX);
        y[t] = 1.f;
    }
    __syncthreads();
    {
        float dacc = 1.f;
        int cur = 0;
        for (int l = 0; l < L; l++){
            if (t < NPER){
                const float* la = &y[cur*NPER];
                float s = 0.f;
                int nq = (dc + 3) >> 2;
                const u16x4* cp = (const u16x4*)(csrcp + (size_t)(gbase + t)*DEGMAX);
                #pragma unroll 1
                for (int jq = 0; jq < nq; jq++){
                    u16x4 oc = cp[jq];
                    s += (la[(int)oc[0]] + la[(int)oc[1]]) + (la[(int)oc[2]] + la[(int)oc[3]]);
                }
                if (nq) s -= (float)(nq*4 - dc) * la[0];
                y[(1^cur)*NPER + t] = s;
                dacc += s;
            }
            __syncthreads();
            cur ^= 1;
        }
        if (t < NPER) y[2*NPER + t] = rsqrtf(fmaxf(dacc, 1e-12f));
    }
    __syncthreads();

    float4 acc[IT]; int cv[IT]; float dv[IT];
    #pragma unroll
    for (int it = 0; it < IT; it++){
        int v = (t >> 3) + 128*it;
        dv[it] = y[2*NPER + v];
        cv[it] = min(cnt[gbase + v], DEGMAX);
    }
    __syncthreads();                          // dv read before staging overwrites y
    #pragma unroll
    for (int it = 0; it < IT; it++){
        int v = (t >> 3) + 128*it;
        float d = dv[it];
        float4 w = *(const float4*)&X[(size_t)(gbase + v)*128 + fo];
        w.x*=d; w.y*=d; w.z*=d; w.w*=d;
        acc[it] = w;
        *(float4*)&y[v*32 + f4] = w;
    }
    __syncthreads();
    for (int l = 0; l < L; l++){
        float4 s[IT];
        #pragma unroll
        for (int it = 0; it < IT; it++){
            float4 ss = make_float4(0.f,0.f,0.f,0.f);
            int c = cv[it];
            int nq = (c + 3) >> 2;
            const u16x4* cp = (const u16x4*)(csrcp + (size_t)(gbase + (t >> 3) + 128*it)*DEGMAX);
            #pragma unroll 1
            for (int jq = 0; jq < nq; jq++){
                u16x4 oc = cp[jq];
                float4 w0 = *(const float4*)&y[((int)oc[0])*32 + f4];
                float4 w1 = *(const float4*)&y[((int)oc[1])*32 + f4];
                float4 w2 = *(const float4*)&y[((int)oc[2])*32 + f4];
                float4 w3 = *(const float4*)&y[((int)oc[3])*32 + f4];
                ss.x += (w0.x + w1.x) + (w2.x + w3.x);
                ss.y += (w0.y + w1.y) + (w2.y + w3.y);
                ss.z += (w0.z + w1.z) + (w2.z + w3.z);
                ss.w += (w0.w + w1.w) + (w2.w + w3.w);
            }
            if (nq){
                float fp = (float)(nq*4 - c);
                float4 z = *(const float4*)&y[f4];          // row 0
                ss.x -= fp*z.x; ss.y -= fp*z.y; ss.z -= fp*z.z; ss.w -= fp*z.w;
            }
            s[it] = ss;
        }
        __syncthreads();
        #pragma unroll
        for (int it = 0; it < IT; it++){
            int v = (t >> 3) + 128*it;
            *(float4*)&y[v*32 + f4] = s[it];
            acc[it].x+=s[it].x; acc[it].y+=s[it].y; acc[it].z+=s[it].z; acc[it].w+=s[it].w;
        }
        __syncthreads();
    }
    #pragma unroll
    for (int it = 0; it < IT; it++){
        int v = (t >> 3) + 128*it;
        float d = dv[it];
        float4 w = acc[it];
        w.x*=d; w.y*=d; w.z*=d; w.w*=d;
        *(float4*)&OUT[(size_t)(gbase + v)*128 + fo] = w;
    }
}

// ---------------- split-bf16 MFMA GEMM: Y = X(Mx128) @ W(128x128) + bias ----------------
// W (hi/lo) staged once in LDS; A loaded straight to registers (no cross-wave A reuse).
template<int RT>
__global__ __launch_bounds__(256) void k_gemm_mfma(const float* __restrict__ X,
        const float* __restrict__ W, const float* __restrict__ bias, float* __restrict__ Y){
    __shared__ short wsh[128*136];
    __shared__ short wsl[128*136];
    __shared__ float bsh[128];
    int t = threadIdx.x;
    for (int e = t; e < 16384; e += 256){
        int k = e >> 7, n = e & 127;
        short hi, lo; split_bf16(W[e], hi, lo);
        wsh[n*136 + k] = hi; wsl[n*136 + k] = lo;
    }
    if (t < 128) bsh[t] = bias[t];
    __syncthreads();
    int wave = t >> 6, lane = t & 63;
    int ln = lane & 15, q = lane >> 4;
    size_t rb0 = (size_t)blockIdx.x * (64*RT);
    for (int rt = 0; rt < RT; rt++){
        size_t rb = rb0 + (size_t)rt*64;
        const float* xrow = &X[(rb + wave*16 + ln)*128 + q*8];
        f32x4 acc[8];
        #pragma unroll
        for (int i = 0; i < 8; i++) acc[i] = (f32x4){0.f,0.f,0.f,0.f};
        #pragma unroll
        for (int kc = 0; kc < 4; kc++){
            float4 xa = *(const float4*)(xrow + kc*32);
            float4 xb = *(const float4*)(xrow + kc*32 + 4);
            bf16x8 ah, al; short hi, lo;
            split_bf16(xa.x, hi, lo); ah[0]=hi; al[0]=lo;
            split_bf16(xa.y, hi, lo); ah[1]=hi; al[1]=lo;
            split_bf16(xa.z, hi, lo); ah[2]=hi; al[2]=lo;
            split_bf16(xa.w, hi, lo); ah[3]=hi; al[3]=lo;
            split_bf16(xb.x, hi, lo); ah[4]=hi; al[4]=lo;
            split_bf16(xb.y, hi, lo); ah[5]=hi; al[5]=lo;
            split_bf16(xb.z, hi, lo); ah[6]=hi; al[6]=lo;
            split_bf16(xb.w, hi, lo); ah[7]=hi; al[7]=lo;
            #pragma unroll
            for (int nt = 0; nt < 8; nt++){
                int wo = (nt*16 + ln)*136 + kc*32 + q*8;
                bf16x8 bh = *(const bf16x8*)&wsh[wo];
                bf16x8 bl = *(const bf16x8*)&wsl[wo];
                acc[nt] = __builtin_amdgcn_mfma_f32_16x16x32_bf16(ah, bh, acc[nt], 0, 0, 0);
                acc[nt] = __builtin_amdgcn_mfma_f32_16x16x32_bf16(ah, bl, acc[nt], 0, 0, 0);
                acc[nt] = __builtin_amdgcn_mfma_f32_16x16x32_bf16(al, bh, acc[nt], 0, 0, 0);
            }
        }
        #pragma unroll
        for (int nt = 0; nt < 8; nt++){
            int c = nt*16 + ln;
            float bb = bsh[c];
            #pragma unroll
            for (int r = 0; r < 4; r++){
                Y[(rb + wave*16 + q*4 + r)*128 + c] = acc[nt][r] + bb;
            }
        }
    }
}

// ---------------- fused pooling: score + top-k + scatter + edge remap + next CSR build ----------------
template<int NPER, bool BUILD>
__global__ __launch_bounds__(512) void k_pooltop(const float* __restrict__ h, const float* __restrict__ p,
        const float* __restrict__ beta, const int* __restrict__ cnt,
        const int* __restrict__ esrc_in, const int* __restrict__ edst_in,
        int* __restrict__ esrc_out, int* __restrict__ edst_out,
        int* __restrict__ cnt_next, unsigned short* __restrict__ csrcp,
        float* __restrict__ hout, int mask){
    __shared__ float q[128];
    __shared__ float sc[NPER];
    __shared__ float th[NPER];
    __shared__ int  nid[NPER];
    __shared__ float red[64];
    const int K = NPER/2;
    int g = blockIdx.x, t = threadIdx.x, gbase = g*NPER;
    float b0 = beta[0], b1 = beta[1];
    if (BUILD && t < K) cnt_next[g*K + t] = 0;
    if (t < 64){ float a = p[t], b = p[t+64]; red[t] = a*a + b*b; }
    __syncthreads();
    if (t == 0){ float s = 0.f; for (int i = 0; i < 64; i++) s += red[i]; red[0] = sqrtf(s); }
    __syncthreads();
    if (t < 128) q[t] = b0 * p[t] / red[0];
    __syncthreads();
    if (t < NPER){
        const float4* hr = (const float4*)(h + (size_t)(gbase + t)*128);
        const float4* q4 = (const float4*)q;
        float s = 0.f;
        #pragma unroll 8
        for (int j = 0; j < 32; j++){
            float4 a = hr[j], b = q4[j];
            s += a.x*b.x + a.y*b.y + a.z*b.z + a.w*b.w;
        }
        s += b1 * (float)cnt[gbase + t];
        sc[t] = s;
    }
    __syncthreads();
    if (t < NPER){
        float s = sc[t];
        int rank = 0;
        for (int j = 0; j < NPER; j++){
            float sj = sc[j];
            rank += (sj > s) || (sj == s && j < t);   // stable tie-break = lax.top_k
        }
        nid[t] = (rank < K) ? (g*K + rank) : -1;
        th[t] = tanhf(s);
    }
    __syncthreads();
    for (int base = t; base < NPER*32; base += 512){
        int v = base >> 5, f4 = base & 31;
        int ni = nid[v];
        if (ni >= 0){
            float tt = th[v];
            float4 w = *(const float4*)&h[(size_t)(gbase + v)*128 + f4*4];
            w.x*=tt; w.y*=tt; w.z*=tt; w.w*=tt;
            *(float4*)&hout[(size_t)ni*128 + f4*4] = w;
        }
    }
    if (BUILD){
        for (int i = t; i < EPG; i += 512){
            int e = g*EPG + i;
            int d = edst_in[e];
            if (d < 0) continue;
            int s_ = esrc_in[e];
            int ns = nid[s_ - gbase], nd = nid[d - gbase];
            if ((ns | nd) < 0){ edst_out[e] = -1; }
            else {
                esrc_out[e] = ns; edst_out[e] = nd;
                int slot = atomicAdd(&cnt_next[nd], 1);
                if (slot < DEGMAX) csrcp[(size_t)nd*DEGMAX + slot] = (unsigned short)(ns & mask);
            }
        }
    }
}

// ---------------- fused readout: scatter-mean + 2-layer MLP ----------------
__global__ __launch_bounds__(128) void k_meanmlp(const float* __restrict__ h, const float* __restrict__ W1,
        const float* __restrict__ b1, const float* __restrict__ W2, const float* __restrict__ b2,
        float* __restrict__ out){
    __shared__ float mr[128];
    int g = blockIdx.x, t = threadIdx.x;
    float s = 0.f;
    for (int r = 0; r < 64; r++) s += h[((size_t)g*64 + r)*128 + t];
    mr[t] = s * (1.f/64.f);
    __syncthreads();
    if (t < 64){
        float a = b1[t];
        #pragma unroll 8
        for (int k = 0; k < 128; k++) a += mr[k]*W1[k*64 + t];
        a = fmaxf(a, 0.f);
        float r = a * W2[t];
        #pragma unroll
        for (int off = 32; off > 0; off >>= 1) r += __shfl_down(r, off);
        if (t == 0) out[g] = r + b2[0];
    }
}

// ---------------- driver ----------------
extern "C" void kernel_launch(void* const* d_in, const int* in_sizes, int n_in,
                              void* d_out, int out_size, void* d_ws, size_t ws_size,
                              hipStream_t stream){
    (void)in_sizes; (void)n_in; (void)out_size; (void)ws_size;
    const float* x     = (const float*)d_in[0];
    const int*   ei    = (const int*)d_in[1];
    const float* lumpW = (const float*)d_in[3];
    const float* lumpb = (const float*)d_in[4];
    const float* convW[3]    = {(const float*)d_in[5], (const float*)d_in[7], (const float*)d_in[9]};
    const float* convB[3]    = {(const float*)d_in[6], (const float*)d_in[8], (const float*)d_in[10]};
    const float* poolP[3]    = {(const float*)d_in[11], (const float*)d_in[13], (const float*)d_in[15]};
    const float* poolBeta[3] = {(const float*)d_in[12], (const float*)d_in[14], (const float*)d_in[16]};
    const float* lin1W = (const float*)d_in[17];
    const float* lin1b = (const float*)d_in[18];
    const float* lin2W = (const float*)d_in[19];
    const float* lin2b = (const float*)d_in[20];
    float* out = (float*)d_out;

    char* w8 = (char*)d_ws;
    size_t off = 0;
    auto alloc = [&](size_t bytes)->char*{
        char* p = w8 + off; off += (bytes + 255) & ~(size_t)255; return p;
    };
    float* A     = (float*)alloc((size_t)65536*128*4);
    float* Bb    = (float*)alloc((size_t)65536*128*4);
    float* Cc    = (float*)alloc((size_t)32768*128*4);
    int*   srcA  = (int*)alloc((size_t)E_*4);
    int*   dstA  = (int*)alloc((size_t)E_*4);
    // csr1/csr2/csr3 + cnt1 contiguous: one memset zeroes rows (pad slots must be 0)
    unsigned short* csr1 = (unsigned short*)alloc((size_t)65536*DEGMAX*2);
    unsigned short* csr2 = (unsigned short*)alloc((size_t)32768*DEGMAX*2);
    unsigned short* csr3 = (unsigned short*)alloc((size_t)16384*DEGMAX*2);
    int*   cntA  = (int*)alloc((size_t)(65536+32768+16384)*4);
    int*   cnt1 = cntA, *cnt2 = cntA + 65536, *cnt3 = cntA + 98304;

    dim3 b256(256);

    size_t zbytes = (size_t)(65536+32768+16384)*DEGMAX*2 + (size_t)65536*4;
    hipMemsetAsync(csr1, 0, zbytes, stream);
    k_gemm_mfma<4><<<256, b256, 0, stream>>>(x, lumpW, lumpb, A);
    k_build1<<<E_/256, b256, 0, stream>>>(ei, cnt1, csr1);

    // ----- stage 1: conv1 (L=4, nper=512), pool -> 256/graph -----
    k_prop<512,4,4><<<dim3(G_,4), 1024, 0, stream>>>(cnt1, csr1, A, Bb);
    k_gemm_mfma<4><<<256, b256, 0, stream>>>(Bb, convW[0], convB[0], A);
    k_pooltop<512,true><<<G_, 512, 0, stream>>>(A, poolP[0], poolBeta[0], cnt1,
            ei, ei + E_, srcA, dstA, cnt2, csr2, Cc, 255);

    // ----- stage 2: conv2 (L=2, nper=256), pool -> 128/graph -----
    k_prop<256,2,2><<<dim3(G_,4), 1024, 0, stream>>>(cnt2, csr2, Cc, Bb);
    k_gemm_mfma<2><<<256, b256, 0, stream>>>(Bb, convW[1], convB[1], A);
    k_pooltop<256,true><<<G_, 512, 0, stream>>>(A, poolP[1], poolBeta[1], cnt2,
            srcA, dstA, srcA, dstA, cnt3, csr3, Cc, 127);

    // ----- stage 3: conv3 (L=2, nper=128), pool -> 64/graph -----
    k_prop<128,2,1><<<dim3(G_,4), 1024, 0, stream>>>(cnt3, csr3, Cc, Bb);
    k_gemm_mfma<1><<<256, b256, 0, stream>>>(Bb, convW[2], convB[2], A);
    k_pooltop<128,false><<<G_, 512, 0, stream>>>(A, poolP[2], poolBeta[2], cnt3,
            nullptr, nullptr, nullptr, nullptr, nullptr, nullptr, Cc, 0);

    // ----- readout -----
    k_meanmlp<<<G_, 128, 0, stream>>>(Cc, lin1W, lin1b, lin2W, lin2b, out);
}